// Round 6
// baseline (408.704 us; speedup 1.0000x reference)
//
#include <hip/hip_runtime.h>
#include <stdint.h>

#define BATCH 8
#define L_SEQ 2048
#define D_MODEL 512
#define TOPK 7
#define BM 128
#define BN 128
#define BK 32
#define LK 40   // LDS row stride (f16) for ds_write-staged GEMM
#define LT 136  // LDS t-stride for epilogue transpose tile

typedef _Float16 f16x8 __attribute__((ext_vector_type(8)));
typedef __attribute__((ext_vector_type(4))) float f32x4;
typedef unsigned short u16;
typedef unsigned int u32;

__device__ __forceinline__ u16 f2h(float f) {
    union { _Float16 h; u16 u; } v; v.h = (_Float16)f; return v.u;
}

// async 16B/lane global->LDS (m97). Dest = wave-uniform base + lane*16.
__device__ __forceinline__ void load_lds16(const u16* g, u16* l) {
    __builtin_amdgcn_global_load_lds(
        (const __attribute__((address_space(1))) u32*)(g),
        (__attribute__((address_space(3))) u32*)(l), 16, 0, 0);
}

// ---------------- fused QKV projection GEMM (prefetch-pipelined) ----------------
// z=0: Qproj -> QT[b][d][t] (transposed)   z=1: Kproj -> KT   z=2: Vproj -> V[b][t][d]
// 1D grid, id = bmL + 8*(bn + 4*(bmH + 16*z)): the 4 bn-blocks of one (bm,z)
// share id%8 -> likely same XCD -> A-tile fetched once per XCD.
__global__ __launch_bounds__(256) void gemm_qkv(
    const float* __restrict__ Xq, const float* __restrict__ Xk, const float* __restrict__ Xv,
    const u16* __restrict__ Wqt, const u16* __restrict__ Wkt, const u16* __restrict__ Wvt,
    const float* __restrict__ bq, const float* __restrict__ bk, const float* __restrict__ bv,
    u16* __restrict__ QT, u16* __restrict__ KT, u16* __restrict__ Vout)
{
    __shared__ __align__(16) char smem[20480];
    u16* lA = (u16*)smem;            // 10240 B (128 x 40 f16)
    u16* lB = (u16*)(smem + 10240);  // 10240 B
    u16* lT = (u16*)smem;            // epilogue overlay, 17408 B

    const int tid = threadIdx.x;
    const int id = blockIdx.x;
    const int bmL = id & 7;
    const int bn  = (id >> 3) & 3;
    const int bmH = (id >> 5) & 15;
    const int z   = id >> 9;
    const int bm  = bmH * 8 + bmL;
    const int lane = tid & 63, wave = tid >> 6;
    const int wm = wave >> 1, wn = wave & 1;
    const int l15 = lane & 15, quad = lane >> 4;

    const float* A  = (z == 0) ? Xq  : (z == 1) ? Xk  : Xv;
    const u16*   Bt = (z == 0) ? Wqt : (z == 1) ? Wkt : Wvt;
    const float* bias = (z == 0) ? bq : (z == 1) ? bk : bv;

    float4 pA[4]; uint4 pB[2];
    #pragma unroll
    for (int j = 0; j < 4; ++j) {
        int idx = tid + j * 256; int row = idx >> 3, c4 = (idx & 7) * 4;
        pA[j] = *(const float4*)(A + (long)(bm * BM + row) * D_MODEL + c4);
    }
    #pragma unroll
    for (int j = 0; j < 2; ++j) {
        int idx = tid + j * 256; int row = idx >> 2, c8 = (idx & 3) * 8;
        pB[j] = *(const uint4*)(Bt + (long)(bn * BN + row) * D_MODEL + c8);
    }

    f32x4 acc[4][4] = {};

    for (int k0 = 0; k0 < D_MODEL; k0 += BK) {
        #pragma unroll
        for (int j = 0; j < 4; ++j) {
            int idx = tid + j * 256; int row = idx >> 3, c4 = (idx & 7) * 4;
            ushort4 pa;
            pa.x = f2h(pA[j].x); pa.y = f2h(pA[j].y);
            pa.z = f2h(pA[j].z); pa.w = f2h(pA[j].w);
            *(ushort4*)&lA[row * LK + c4] = pa;
        }
        #pragma unroll
        for (int j = 0; j < 2; ++j) {
            int idx = tid + j * 256; int row = idx >> 2, c8 = (idx & 3) * 8;
            *(uint4*)&lB[row * LK + c8] = pB[j];
        }
        __syncthreads();

        if (k0 + BK < D_MODEL) {   // prefetch next tile; latency hides behind MFMA
            #pragma unroll
            for (int j = 0; j < 4; ++j) {
                int idx = tid + j * 256; int row = idx >> 3, c4 = (idx & 7) * 4;
                pA[j] = *(const float4*)(A + (long)(bm * BM + row) * D_MODEL + k0 + BK + c4);
            }
            #pragma unroll
            for (int j = 0; j < 2; ++j) {
                int idx = tid + j * 256; int row = idx >> 2, c8 = (idx & 3) * 8;
                pB[j] = *(const uint4*)(Bt + (long)(bn * BN + row) * D_MODEL + k0 + BK + c8);
            }
        }

        f16x8 fa[4], fb[4];
        #pragma unroll
        for (int i = 0; i < 4; ++i)
            fa[i] = *(const f16x8*)&lA[(wm * 64 + i * 16 + l15) * LK + quad * 8];
        #pragma unroll
        for (int j = 0; j < 4; ++j)
            fb[j] = *(const f16x8*)&lB[(wn * 64 + j * 16 + l15) * LK + quad * 8];
        #pragma unroll
        for (int i = 0; i < 4; ++i)
            #pragma unroll
            for (int j = 0; j < 4; ++j)
                acc[i][j] = __builtin_amdgcn_mfma_f32_16x16x32_f16(fa[i], fb[j], acc[i][j], 0, 0, 0);
        __syncthreads();
    }

    if (z < 2) {
        // transposed epilogue: out[b][d][t]
        u16* out = (z == 0) ? QT : KT;
        const int t0 = (bm * BM) & (L_SEQ - 1);
        const int bb = (bm * BM) >> 11;
        #pragma unroll
        for (int h = 0; h < 2; ++h) {
            __syncthreads();
            if (wn == h) {
                #pragma unroll
                for (int j = 0; j < 4; ++j) {
                    int dloc = j * 16 + l15;
                    float bvv = bias[bn * BN + h * 64 + dloc];
                    #pragma unroll
                    for (int i = 0; i < 4; ++i) {
                        int trow = wm * 64 + i * 16 + quad * 4;
                        #pragma unroll
                        for (int r = 0; r < 4; ++r)
                            lT[dloc * LT + trow + r] = f2h(acc[i][j][r] + bvv);
                    }
                }
            }
            __syncthreads();
            int dloc = tid >> 2, q4 = tid & 3;
            long base = ((long)(bb * D_MODEL + bn * BN + h * 64 + dloc)) * L_SEQ + t0;
            #pragma unroll
            for (int s = 0; s < 4; ++s) {
                int c = q4 * 4 + s;
                *(uint4*)(out + base + c * 8) = *(const uint4*)&lT[dloc * LT + c * 8];
            }
        }
    } else {
        #pragma unroll
        for (int i = 0; i < 4; ++i) {
            int row = bm * BM + wm * 64 + i * 16 + quad * 4;
            #pragma unroll
            for (int j = 0; j < 4; ++j) {
                int col = bn * BN + wn * 64 + j * 16 + l15;
                float bvv = bias[col];
                #pragma unroll
                for (int r = 0; r < 4; ++r)
                    Vout[(long)(row + r) * D_MODEL + col] = f2h(acc[i][j][r] + bvv);
            }
        }
    }
}

// ---------------- final projection GEMM: A f16 via global_load_lds, C fp32 ----------------
__global__ __launch_bounds__(256, 4) void gemm_f16_out32(
    const u16* __restrict__ A, const u16* __restrict__ Bt,
    const float* __restrict__ bias, float* __restrict__ Cp, int N, int K)
{
    __shared__ __align__(16) u16 lA[BM * BK];
    __shared__ __align__(16) u16 lB[BN * BK];

    const int tid = threadIdx.x;
    const int bn = blockIdx.x, bm = blockIdx.y;
    const int lane = tid & 63, wave = tid >> 6;
    const int wm = wave >> 1, wn = wave & 1;
    const int l15 = lane & 15, quad = lane >> 4;

    const int s0 = wave * 64 + lane, s1 = s0 + 256;
    const int r0 = s0 >> 2, c0 = (s0 & 3) ^ ((r0 >> 1) & 3);
    const int r1 = s1 >> 2, c1 = (s1 & 3) ^ ((r1 >> 1) & 3);
    const u16* gA0 = A + (long)(bm * BM + r0) * K + c0 * 8;
    const u16* gA1 = A + (long)(bm * BM + r1) * K + c1 * 8;
    const u16* gB0 = Bt + (long)(bn * BN + r0) * K + c0 * 8;
    const u16* gB1 = Bt + (long)(bn * BN + r1) * K + c1 * 8;
    u16* lA0 = &lA[wave * 512]; u16* lA1 = &lA[2048 + wave * 512];
    u16* lB0 = &lB[wave * 512]; u16* lB1 = &lB[2048 + wave * 512];

    f32x4 acc[4][4] = {};

    for (int k0 = 0; k0 < K; k0 += BK) {
        load_lds16(gA0, lA0); load_lds16(gA1, lA1);
        load_lds16(gB0, lB0); load_lds16(gB1, lB1);
        gA0 += BK; gA1 += BK; gB0 += BK; gB1 += BK;
        __syncthreads();

        f16x8 fa[4], fb[4];
        #pragma unroll
        for (int i = 0; i < 4; ++i) {
            int m = wm * 64 + i * 16 + l15;
            int cs = quad ^ ((m >> 1) & 3);
            fa[i] = *(const f16x8*)&lA[m * 32 + cs * 8];
        }
        #pragma unroll
        for (int j = 0; j < 4; ++j) {
            int n = wn * 64 + j * 16 + l15;
            int cs = quad ^ ((n >> 1) & 3);
            fb[j] = *(const f16x8*)&lB[n * 32 + cs * 8];
        }
        #pragma unroll
        for (int i = 0; i < 4; ++i)
            #pragma unroll
            for (int j = 0; j < 4; ++j)
                acc[i][j] = __builtin_amdgcn_mfma_f32_16x16x32_f16(fa[i], fb[j], acc[i][j], 0, 0, 0);
        __syncthreads();
    }

    #pragma unroll
    for (int i = 0; i < 4; ++i) {
        int row = bm * BM + wm * 64 + i * 16 + quad * 4;
        #pragma unroll
        for (int j = 0; j < 4; ++j) {
            int col = bn * BN + wn * 64 + j * 16 + l15;
            float bvv = bias[col];
            #pragma unroll
            for (int r = 0; r < 4; ++r)
                Cp[(long)(row + r) * N + col] = acc[i][j][r] + bvv;
        }
    }
}

// ---------------- shared 2048-pt in-LDS FFT: radix-2^2 (5 fused pairs) + radix-2 ----------------
// Direction set by the twiddle table sign. Caller syncs before; func syncs after.
__device__ __forceinline__ void fft2048_lds(
    float* Zr, float* Zi, const float* Twr, const float* Twi, int tid)
{
    #pragma unroll
    for (int s = 0; s < 10; s += 2) {
        #pragma unroll
        for (int u = 0; u < 2; ++u) {
            int idx = tid + u * 256;               // [0,512) radix-4 groups
            int d1 = 1 << s;
            int pos = idx & (d1 - 1);
            int i0 = ((idx >> s) << (s + 2)) + pos;
            float w1r = Twr[pos << (10 - s)], w1i = Twi[pos << (10 - s)];
            float w2r = Twr[pos << (9 - s)],  w2i = Twi[pos << (9 - s)];
            int p2 = pos + d1;
            float w3r = Twr[p2 << (9 - s)],   w3i = Twi[p2 << (9 - s)];
            float ar = Zr[i0],          ai = Zi[i0];
            float br = Zr[i0 + d1],     bi = Zi[i0 + d1];
            float cr = Zr[i0 + 2 * d1], ci = Zi[i0 + 2 * d1];
            float dr = Zr[i0 + 3 * d1], di = Zi[i0 + 3 * d1];
            float t1r = br * w1r - bi * w1i, t1i = br * w1i + bi * w1r;
            float Ar = ar + t1r, Ai = ai + t1i, Br = ar - t1r, Bi = ai - t1i;
            float t2r = dr * w1r - di * w1i, t2i = dr * w1i + di * w1r;
            float Cr = cr + t2r, Ci = ci + t2i, Dr = cr - t2r, Di = ci - t2i;
            float u1r = Cr * w2r - Ci * w2i, u1i = Cr * w2i + Ci * w2r;
            float u2r = Dr * w3r - Di * w3i, u2i = Dr * w3i + Di * w3r;
            Zr[i0]          = Ar + u1r; Zi[i0]          = Ai + u1i;
            Zr[i0 + 2 * d1] = Ar - u1r; Zi[i0 + 2 * d1] = Ai - u1i;
            Zr[i0 + d1]     = Br + u2r; Zi[i0 + d1]     = Bi + u2i;
            Zr[i0 + 3 * d1] = Br - u2r; Zi[i0 + 3 * d1] = Bi - u2i;
        }
        __syncthreads();
    }
    #pragma unroll
    for (int j = 0; j < 4; ++j) {                  // leftover stage s=10
        int idx = tid + j * 256;
        float wr = Twr[idx], wi = Twi[idx];
        float ar = Zr[idx], ai = Zi[idx];
        float br = Zr[idx + 1024], bi = Zi[idx + 1024];
        float tr = br * wr - bi * wi, ti = br * wi + bi * wr;
        Zr[idx] = ar + tr; Zi[idx] = ai + ti;
        Zr[idx + 1024] = ar - tr; Zi[idx + 1024] = ai - ti;
    }
    __syncthreads();
}

// ---------------- FFT autocorrelation forward (inputs [b][d][t]) ----------------
__global__ __launch_bounds__(256) void fft_corr_fwd(
    const u16* __restrict__ QT, const u16* __restrict__ KT, float* __restrict__ S)
{
    __shared__ float Zr[2048], Zi[2048];
    __shared__ float Sr[2048], Si[2048];
    __shared__ float Twr[1024], Twi[1024];
    const int tid = threadIdx.x;
    const int b = blockIdx.x >> 6, dg = blockIdx.x & 63;

    #pragma unroll
    for (int j = 0; j < 4; ++j) {
        int i = tid + j * 256;
        float ang = -6.28318530717958647692f * (float)i * (1.0f / 2048.0f);
        float sn, cs; __sincosf(ang, &sn, &cs);
        Twr[i] = cs; Twi[i] = sn;
    }
    #pragma unroll
    for (int j = 0; j < 8; ++j) { Sr[tid + j * 256] = 0.f; Si[tid + j * 256] = 0.f; }

    for (int g = 0; g < 8; ++g) {
        int d = dg * 8 + g;
        const u16* qrow = QT + ((long)b * D_MODEL + d) * L_SEQ;
        const u16* krow = KT + ((long)b * D_MODEL + d) * L_SEQ;
        __syncthreads();   // Z reuse guard
        union { uint4 u; _Float16 h[8]; } xq, xk;
        xq.u = *(const uint4*)(qrow + tid * 8);
        xk.u = *(const uint4*)(krow + tid * 8);
        #pragma unroll
        for (int j = 0; j < 8; ++j) {
            int t = tid * 8 + j;
            int tr = (int)(__brev((unsigned)t) >> 21);
            Zr[tr] = (float)xq.h[j];
            Zi[tr] = (float)xk.h[j];
        }
        __syncthreads();
        fft2048_lds(Zr, Zi, Twr, Twi, tid);
        #pragma unroll
        for (int j = 0; j < 8; ++j) {
            int f = tid + j * 256;
            int fm = (2048 - f) & 2047;
            float Xr = Zr[f], Xi = Zi[f], Xmr = Zr[fm], Xmi = Zi[fm];
            float qr = 0.5f * (Xr + Xmr), qi = 0.5f * (Xi - Xmi);
            float dr = Xr - Xmr,          di = Xi + Xmi;
            float kr = 0.5f * di,         ki = -0.5f * dr;
            Sr[f] += qr * kr + qi * ki;
            Si[f] += qi * kr - qr * ki;
        }
    }
    __syncthreads();
    #pragma unroll
    for (int j = 0; j < 8; ++j) {
        int f = tid + j * 256;
        atomicAdd(&S[((long)b * 2048 + f) * 2 + 0], Sr[f]);
        atomicAdd(&S[((long)b * 2048 + f) * 2 + 1], Si[f]);
    }
}

// ---------------- finalize: g = IFFT(sum_b S); top-7; direct-DFT weights; softmax ----------------
__global__ __launch_bounds__(256) void finalize(
    const float* __restrict__ S, int* __restrict__ selIdx, float* __restrict__ selW)
{
    __shared__ float Zr[2048], Zi[2048];
    __shared__ float Twr[1024], Twi[1024];
    __shared__ float rv[256];
    __shared__ int   ri[256];
    __shared__ int   sidx[TOPK];
    __shared__ float pbuf[256];
    __shared__ float wbuf[BATCH][TOPK];
    const int tid = threadIdx.x;

    #pragma unroll
    for (int j = 0; j < 4; ++j) {      // inverse twiddles (+angle)
        int i = tid + j * 256;
        float ang = 6.28318530717958647692f * (float)i * (1.0f / 2048.0f);
        float sn, cs; __sincosf(ang, &sn, &cs);
        Twr[i] = cs; Twi[i] = sn;
    }
    #pragma unroll
    for (int j = 0; j < 8; ++j) {      // batch-summed spectrum, bit-reversed placement
        int f = tid + j * 256;
        float sr = 0.f, si = 0.f;
        #pragma unroll
        for (int b = 0; b < BATCH; ++b) {
            sr += S[((long)b * 2048 + f) * 2 + 0];
            si += S[((long)b * 2048 + f) * 2 + 1];
        }
        int fr = (int)(__brev((unsigned)f) >> 21);
        Zr[fr] = sr; Zi[fr] = si;
    }
    __syncthreads();
    fft2048_lds(Zr, Zi, Twr, Twi, tid);
    // Zr[t] == g[t] up to positive scale; top-7 (lowest-index tie-break)
    for (int it = 0; it < TOPK; ++it) {
        float best = -1e30f; int bi = 0x7fffffff;
        for (int t = tid; t < L_SEQ; t += 256) {
            float v = Zr[t];
            if (v > best || (v == best && t < bi)) { best = v; bi = t; }
        }
        rv[tid] = best; ri[tid] = bi;
        __syncthreads();
        for (int s = 128; s > 0; s >>= 1) {
            if (tid < s) {
                float v2 = rv[tid + s]; int i2 = ri[tid + s];
                if (v2 > rv[tid] || (v2 == rv[tid] && i2 < ri[tid])) { rv[tid] = v2; ri[tid] = i2; }
            }
            __syncthreads();
        }
        if (tid == 0) { sidx[it] = ri[0]; Zr[ri[0]] = -1e30f; }
        __syncthreads();
    }
    // weights: mean_value[b,tau] = (1/(2048*512)) * sum_f Re(S[b,f] e^{+2pi i f tau/2048})
    int pair = tid >> 2, i4 = tid & 3;
    float part = 0.f;
    if (pair < BATCH * TOPK) {
        int b = pair / TOPK, k = pair % TOPK, tau = sidx[k];
        for (int n = 0; n < 512; ++n) {
            int f = i4 + 4 * n;
            int m = (f * tau) & 2047;
            float cr, ci;
            if (m < 1024) { cr = Twr[m]; ci = Twi[m]; }
            else          { cr = -Twr[m - 1024]; ci = -Twi[m - 1024]; }
            part += S[((long)b * 2048 + f) * 2 + 0] * cr
                  - S[((long)b * 2048 + f) * 2 + 1] * ci;
        }
    }
    pbuf[tid] = part;
    __syncthreads();
    if (tid < BATCH * TOPK) {
        float s = pbuf[tid * 4] + pbuf[tid * 4 + 1] + pbuf[tid * 4 + 2] + pbuf[tid * 4 + 3];
        wbuf[tid / TOPK][tid % TOPK] = s * (1.0f / (2048.0f * 512.0f));
    }
    __syncthreads();
    if (tid < BATCH) {
        float mx = -1e30f;
        #pragma unroll
        for (int k = 0; k < TOPK; ++k) mx = fmaxf(mx, wbuf[tid][k]);
        float e[TOPK]; float sum = 0.f;
        #pragma unroll
        for (int k = 0; k < TOPK; ++k) { e[k] = expf(wbuf[tid][k] - mx); sum += e[k]; }
        #pragma unroll
        for (int k = 0; k < TOPK; ++k) selW[tid * TOPK + k] = e[k] / sum;
    }
    if (tid < TOPK) selIdx[tid] = sidx[tid];
}

// Wt[n][k] = W[k][n], fp32 -> fp16; z picks the weight matrix
__global__ __launch_bounds__(256) void transposeW4(
    const float* __restrict__ Wq, const float* __restrict__ Wk,
    const float* __restrict__ Wv, const float* __restrict__ Wo, u16* __restrict__ dstBase)
{
    __shared__ float t[32][33];
    const int z = blockIdx.z;
    const float* src = (z == 0) ? Wq : (z == 1) ? Wk : (z == 2) ? Wv : Wo;
    u16* dst = dstBase + (long)z * D_MODEL * D_MODEL;
    int tx = threadIdx.x & 31, ty = threadIdx.x >> 5;
    int c0 = blockIdx.x * 32, r0 = blockIdx.y * 32;
    #pragma unroll
    for (int r = ty; r < 32; r += 8)
        t[r][tx] = src[(long)(r0 + r) * D_MODEL + c0 + tx];
    __syncthreads();
    #pragma unroll
    for (int r = ty; r < 32; r += 8)
        dst[(long)(c0 + r) * D_MODEL + r0 + tx] = f2h(t[tx][r]);
}

// attn[b,l,:] = sum_k w[b][k] * V[b,(l+idx[k])%L,:]
__global__ __launch_bounds__(256) void gather_agg(
    const u16* __restrict__ V, const int* __restrict__ selIdx,
    const float* __restrict__ selW, u16* __restrict__ outB)
{
    __shared__ int si[TOPK];
    __shared__ float sw[TOPK];
    long flat = (long)blockIdx.x * 256 + threadIdx.x;
    int b  = (int)(flat >> 17);
    int l  = (int)((flat >> 6) & (L_SEQ - 1));
    int d8 = (int)(flat & 63);
    if (threadIdx.x < TOPK) {
        si[threadIdx.x] = selIdx[threadIdx.x];
        sw[threadIdx.x] = selW[b * TOPK + threadIdx.x];
    }
    __syncthreads();
    const uint4* v8 = (const uint4*)(V + (long)b * L_SEQ * D_MODEL);
    float a[8] = {0,0,0,0,0,0,0,0};
    #pragma unroll
    for (int k = 0; k < TOPK; ++k) {
        int src = (l + si[k]) & (L_SEQ - 1);
        union { uint4 u; _Float16 h[8]; } x;
        x.u = v8[src * 64 + d8];
        float w = sw[k];
        #pragma unroll
        for (int q = 0; q < 8; ++q) a[q] += w * (float)x.h[q];
    }
    union { uint4 u; _Float16 h[8]; } o;
    #pragma unroll
    for (int q = 0; q < 8; ++q) o.h[q] = (_Float16)a[q];
    ((uint4*)outB)[flat] = o.u;
}

extern "C" void kernel_launch(void* const* d_in, const int* in_sizes, int n_in,
                              void* d_out, int out_size, void* d_ws, size_t ws_size,
                              hipStream_t stream)
{
    (void)in_sizes; (void)n_in; (void)out_size; (void)ws_size;
    const float* Xq = (const float*)d_in[0];
    const float* Xk = (const float*)d_in[1];
    const float* Xv = (const float*)d_in[2];
    const float* Wq = (const float*)d_in[3];
    const float* bq = (const float*)d_in[4];
    const float* Wk = (const float*)d_in[5];
    const float* bk = (const float*)d_in[6];
    const float* Wv = (const float*)d_in[7];
    const float* bv = (const float*)d_in[8];
    const float* Wo = (const float*)d_in[9];
    const float* bo = (const float*)d_in[10];

    char* ws = (char*)d_ws;
    const long SLABH = (long)BATCH * L_SEQ * D_MODEL * sizeof(u16);   // 16 MB
    u16* QT   = (u16*)(ws);
    u16* KT   = (u16*)(ws + SLABH);
    u16* Vf   = (u16*)(ws + 2 * SLABH);
    u16* attn = (u16*)(ws + 3 * SLABH);
    const long WSZ = (long)D_MODEL * D_MODEL;
    u16* Wt   = (u16*)(ws + 4 * SLABH);        // 4 x 512 KB: Wq,Wk,Wv,Wo transposed
    u16* Wqt = Wt + 0 * WSZ; u16* Wkt = Wt + 1 * WSZ;
    u16* Wvt = Wt + 2 * WSZ; u16* Wot = Wt + 3 * WSZ;
    float* S   = (float*)(ws + 4 * SLABH + 4 * WSZ * sizeof(u16));
    int*   sIdx = (int*)(S + (long)BATCH * L_SEQ * 2);
    float* sW   = (float*)(sIdx + 8);

    dim3 tb(256);
    transposeW4<<<dim3(16, 16, 4), tb, 0, stream>>>(Wq, Wk, Wv, Wo, Wt);
    hipMemsetAsync(S, 0, (long)BATCH * L_SEQ * 2 * sizeof(float), stream);

    gemm_qkv<<<dim3(1536), tb, 0, stream>>>(Xq, Xk, Xv, Wqt, Wkt, Wvt, bq, bk, bv, QT, KT, Vf);

    fft_corr_fwd<<<dim3(512), tb, 0, stream>>>(QT, KT, S);
    finalize<<<dim3(1), tb, 0, stream>>>(S, sIdx, sW);

    gather_agg<<<(BATCH * L_SEQ * D_MODEL / 8) / 256, tb, 0, stream>>>(Vf, sIdx, sW, attn);

    dim3 gO(D_MODEL / BN, (BATCH * L_SEQ) / BM, 1);
    gemm_f16_out32<<<gO, tb, 0, stream>>>(attn, Wot, bo, (float*)d_out, D_MODEL, D_MODEL);
}

// Round 7
// 344.846 us; speedup vs baseline: 1.1852x; 1.1852x over previous
//
#include <hip/hip_runtime.h>
#include <stdint.h>

#define BATCH 8
#define L_SEQ 2048
#define D_MODEL 512
#define TOPK 7
#define BM 128
#define BN 128
#define BK 32
#define LK 40   // LDS row stride (f16) for ds_write-staged GEMM
#define LT 136  // LDS t-stride for epilogue transpose tile

typedef _Float16 f16x8 __attribute__((ext_vector_type(8)));
typedef __attribute__((ext_vector_type(4))) float f32x4;
typedef unsigned short u16;
typedef unsigned int u32;

__device__ __forceinline__ u16 f2h(float f) {
    union { _Float16 h; u16 u; } v; v.h = (_Float16)f; return v.u;
}

// async 16B/lane global->LDS (m97). Dest = wave-uniform base + lane*16.
__device__ __forceinline__ void load_lds16(const u16* g, u16* l) {
    __builtin_amdgcn_global_load_lds(
        (const __attribute__((address_space(1))) u32*)(g),
        (__attribute__((address_space(3))) u32*)(l), 16, 0, 0);
}

// ---------------- fused QKV projection GEMM (round-5 proven structure) ----------------
// z=0: Qproj -> QT[b][d][t] (transposed)   z=1: Kproj -> KT   z=2: Vproj -> V[b][t][d]
__global__ __launch_bounds__(256) void gemm_qkv(
    const float* __restrict__ Xq, const float* __restrict__ Xk, const float* __restrict__ Xv,
    const u16* __restrict__ Wqt, const u16* __restrict__ Wkt, const u16* __restrict__ Wvt,
    const float* __restrict__ bq, const float* __restrict__ bk, const float* __restrict__ bv,
    u16* __restrict__ QT, u16* __restrict__ KT, u16* __restrict__ Vout)
{
    __shared__ __align__(16) u16 lA[BM * LK];
    __shared__ __align__(16) u16 lB[BN * LK];
    __shared__ __align__(16) u16 lT[64 * LT];

    const int tid = threadIdx.x;
    const int bn = blockIdx.x, bm = blockIdx.y, z = blockIdx.z;
    const int lane = tid & 63, wave = tid >> 6;
    const int wm = wave >> 1, wn = wave & 1;
    const int l15 = lane & 15, quad = lane >> 4;

    const float* A  = (z == 0) ? Xq  : (z == 1) ? Xk  : Xv;
    const u16*   Bt = (z == 0) ? Wqt : (z == 1) ? Wkt : Wvt;
    const float* bias = (z == 0) ? bq : (z == 1) ? bk : bv;

    f32x4 acc[4][4] = {};

    for (int k0 = 0; k0 < D_MODEL; k0 += BK) {
        #pragma unroll
        for (int j = 0; j < 4; ++j) {
            int idx = tid + j * 256;                  // 128x32 fp32 tile / 4
            int row = idx >> 3, c4 = (idx & 7) * 4;
            float4 va = *(const float4*)(A + (long)(bm * BM + row) * D_MODEL + k0 + c4);
            ushort4 pa;
            pa.x = f2h(va.x); pa.y = f2h(va.y); pa.z = f2h(va.z); pa.w = f2h(va.w);
            *(ushort4*)&lA[row * LK + c4] = pa;
        }
        #pragma unroll
        for (int j = 0; j < 2; ++j) {
            int idx = tid + j * 256;                  // 128x32 f16 tile / 8
            int row = idx >> 2, c8 = (idx & 3) * 8;
            *(uint4*)&lB[row * LK + c8] =
                *(const uint4*)(Bt + (long)(bn * BN + row) * D_MODEL + k0 + c8);
        }
        __syncthreads();

        f16x8 fa[4], fb[4];
        #pragma unroll
        for (int i = 0; i < 4; ++i)
            fa[i] = *(const f16x8*)&lA[(wm * 64 + i * 16 + l15) * LK + quad * 8];
        #pragma unroll
        for (int j = 0; j < 4; ++j)
            fb[j] = *(const f16x8*)&lB[(wn * 64 + j * 16 + l15) * LK + quad * 8];
        #pragma unroll
        for (int i = 0; i < 4; ++i)
            #pragma unroll
            for (int j = 0; j < 4; ++j)
                acc[i][j] = __builtin_amdgcn_mfma_f32_16x16x32_f16(fa[i], fb[j], acc[i][j], 0, 0, 0);
        __syncthreads();
    }

    if (z < 2) {
        u16* out = (z == 0) ? QT : KT;
        const int t0 = (bm * BM) & (L_SEQ - 1);
        const int bb = (bm * BM) >> 11;
        #pragma unroll
        for (int h = 0; h < 2; ++h) {
            __syncthreads();
            if (wn == h) {
                #pragma unroll
                for (int j = 0; j < 4; ++j) {
                    int dloc = j * 16 + l15;
                    float bvv = bias[bn * BN + h * 64 + dloc];
                    #pragma unroll
                    for (int i = 0; i < 4; ++i) {
                        int trow = wm * 64 + i * 16 + quad * 4;
                        #pragma unroll
                        for (int r = 0; r < 4; ++r)
                            lT[dloc * LT + trow + r] = f2h(acc[i][j][r] + bvv);
                    }
                }
            }
            __syncthreads();
            int dloc = tid >> 2, q4 = tid & 3;
            long base = ((long)(bb * D_MODEL + bn * BN + h * 64 + dloc)) * L_SEQ + t0;
            #pragma unroll
            for (int s = 0; s < 4; ++s) {
                int c = q4 * 4 + s;
                *(uint4*)(out + base + c * 8) = *(const uint4*)&lT[dloc * LT + c * 8];
            }
        }
    } else {
        #pragma unroll
        for (int i = 0; i < 4; ++i) {
            int row = bm * BM + wm * 64 + i * 16 + quad * 4;
            #pragma unroll
            for (int j = 0; j < 4; ++j) {
                int col = bn * BN + wn * 64 + j * 16 + l15;
                float bvv = bias[col];
                #pragma unroll
                for (int r = 0; r < 4; ++r)
                    Vout[(long)(row + r) * D_MODEL + col] = f2h(acc[i][j][r] + bvv);
            }
        }
    }
}

// ---------------- fused gather + output projection ----------------
// A-tile staging computes attn[b,l,:] = sum_k w[b][k] * V[b,(l+idx)%L,:] on the fly.
// B (Wo^T) staged via global_load_lds (XOR swizzle). C fp32 + bias -> d_out.
__global__ __launch_bounds__(256) void gemm_out_fused(
    const u16* __restrict__ V, const u16* __restrict__ Bt,
    const int* __restrict__ selIdx, const float* __restrict__ selW,
    const float* __restrict__ bias, float* __restrict__ Cp)
{
    __shared__ __align__(16) u16 lA[BM * LK];   // ds_write staged (padded)
    __shared__ __align__(16) u16 lB[BN * BK];   // global_load_lds (unpadded, swizzled)
    __shared__ int   si[TOPK];
    __shared__ float sw[BATCH][TOPK];

    const int tid = threadIdx.x;
    const int bn = blockIdx.x, bm = blockIdx.y;
    const int lane = tid & 63, wave = tid >> 6;
    const int wm = wave >> 1, wn = wave & 1;
    const int l15 = lane & 15, quad = lane >> 4;

    if (tid < TOPK) si[tid] = selIdx[tid];
    if (tid < BATCH * TOPK) sw[tid / TOPK][tid % TOPK] = selW[tid];

    // B staging addresses (m97 pattern)
    const int s0 = wave * 64 + lane, s1 = s0 + 256;
    const int r0 = s0 >> 2, c0 = (s0 & 3) ^ ((r0 >> 1) & 3);
    const int r1 = s1 >> 2, c1 = (s1 & 3) ^ ((r1 >> 1) & 3);
    const u16* gB0 = Bt + (long)(bn * BN + r0) * D_MODEL + c0 * 8;
    const u16* gB1 = Bt + (long)(bn * BN + r1) * D_MODEL + c1 * 8;
    u16* lB0 = &lB[wave * 512]; u16* lB1 = &lB[2048 + wave * 512];

    __syncthreads();   // si/sw visible

    f32x4 acc[4][4] = {};

    for (int k0 = 0; k0 < D_MODEL; k0 += BK) {
        load_lds16(gB0, lB0); load_lds16(gB1, lB1);
        gB0 += BK; gB1 += BK;
        // A staging: 7-tap weighted gather from V
        #pragma unroll
        for (int j = 0; j < 2; ++j) {
            int idx = tid + j * 256;                  // 512 slots: 128 rows x 4 chunks
            int row = idx >> 2, c8 = (idx & 3) * 8;
            int gr = bm * BM + row;
            int b = gr >> 11, l = gr & (L_SEQ - 1);
            float a[8] = {0,0,0,0,0,0,0,0};
            #pragma unroll
            for (int k = 0; k < TOPK; ++k) {
                int src = (l + si[k]) & (L_SEQ - 1);
                union { uint4 u; _Float16 h[8]; } x;
                x.u = *(const uint4*)(V + ((long)b * L_SEQ + src) * D_MODEL + k0 + c8);
                float w = sw[b][k];
                #pragma unroll
                for (int q = 0; q < 8; ++q) a[q] += w * (float)x.h[q];
            }
            union { uint4 u; u16 s[8]; } o;
            #pragma unroll
            for (int q = 0; q < 8; ++q) o.s[q] = f2h(a[q]);
            *(uint4*)&lA[row * LK + c8] = o.u;
        }
        __syncthreads();

        f16x8 fa[4], fb[4];
        #pragma unroll
        for (int i = 0; i < 4; ++i)
            fa[i] = *(const f16x8*)&lA[(wm * 64 + i * 16 + l15) * LK + quad * 8];
        #pragma unroll
        for (int j = 0; j < 4; ++j) {
            int n = wn * 64 + j * 16 + l15;
            int cs = quad ^ ((n >> 1) & 3);
            fb[j] = *(const f16x8*)&lB[n * 32 + cs * 8];
        }
        #pragma unroll
        for (int i = 0; i < 4; ++i)
            #pragma unroll
            for (int j = 0; j < 4; ++j)
                acc[i][j] = __builtin_amdgcn_mfma_f32_16x16x32_f16(fa[i], fb[j], acc[i][j], 0, 0, 0);
        __syncthreads();
    }

    #pragma unroll
    for (int i = 0; i < 4; ++i) {
        int row = bm * BM + wm * 64 + i * 16 + quad * 4;
        #pragma unroll
        for (int j = 0; j < 4; ++j) {
            int col = bn * BN + wn * 64 + j * 16 + l15;
            float bvv = bias[col];
            #pragma unroll
            for (int r = 0; r < 4; ++r)
                Cp[(long)(row + r) * D_MODEL + col] = acc[i][j][r] + bvv;
        }
    }
}

// ---------------- shared 2048-pt in-LDS FFT: radix-2^2 pairs + final radix-2 ----------------
__device__ __forceinline__ void fft2048_lds(
    float* Zr, float* Zi, const float* Twr, const float* Twi, int tid)
{
    #pragma unroll
    for (int s = 0; s < 10; s += 2) {
        #pragma unroll
        for (int u = 0; u < 2; ++u) {
            int idx = tid + u * 256;
            int d1 = 1 << s;
            int pos = idx & (d1 - 1);
            int i0 = ((idx >> s) << (s + 2)) + pos;
            float w1r = Twr[pos << (10 - s)], w1i = Twi[pos << (10 - s)];
            float w2r = Twr[pos << (9 - s)],  w2i = Twi[pos << (9 - s)];
            int p2 = pos + d1;
            float w3r = Twr[p2 << (9 - s)],   w3i = Twi[p2 << (9 - s)];
            float ar = Zr[i0],          ai = Zi[i0];
            float br = Zr[i0 + d1],     bi = Zi[i0 + d1];
            float cr = Zr[i0 + 2 * d1], ci = Zi[i0 + 2 * d1];
            float dr = Zr[i0 + 3 * d1], di = Zi[i0 + 3 * d1];
            float t1r = br * w1r - bi * w1i, t1i = br * w1i + bi * w1r;
            float Ar = ar + t1r, Ai = ai + t1i, Br = ar - t1r, Bi = ai - t1i;
            float t2r = dr * w1r - di * w1i, t2i = dr * w1i + di * w1r;
            float Cr = cr + t2r, Ci = ci + t2i, Dr = cr - t2r, Di = ci - t2i;
            float u1r = Cr * w2r - Ci * w2i, u1i = Cr * w2i + Ci * w2r;
            float u2r = Dr * w3r - Di * w3i, u2i = Dr * w3i + Di * w3r;
            Zr[i0]          = Ar + u1r; Zi[i0]          = Ai + u1i;
            Zr[i0 + 2 * d1] = Ar - u1r; Zi[i0 + 2 * d1] = Ai - u1i;
            Zr[i0 + d1]     = Br + u2r; Zi[i0 + d1]     = Bi + u2i;
            Zr[i0 + 3 * d1] = Br - u2r; Zi[i0 + 3 * d1] = Bi - u2i;
        }
        __syncthreads();
    }
    #pragma unroll
    for (int j = 0; j < 4; ++j) {                  // leftover stage s=10
        int idx = tid + j * 256;
        float wr = Twr[idx], wi = Twi[idx];
        float ar = Zr[idx], ai = Zi[idx];
        float br = Zr[idx + 1024], bi = Zi[idx + 1024];
        float tr = br * wr - bi * wi, ti = br * wi + bi * wr;
        Zr[idx] = ar + tr; Zi[idx] = ai + ti;
        Zr[idx + 1024] = ar - tr; Zi[idx + 1024] = ai - ti;
    }
    __syncthreads();
}

// ---------------- FFT autocorrelation forward (inputs [b][d][t]) ----------------
__global__ __launch_bounds__(256) void fft_corr_fwd(
    const u16* __restrict__ QT, const u16* __restrict__ KT, float* __restrict__ S)
{
    __shared__ float Zr[2048], Zi[2048];
    __shared__ float Sr[2048], Si[2048];
    __shared__ float Twr[1024], Twi[1024];
    const int tid = threadIdx.x;
    const int b = blockIdx.x >> 6, dg = blockIdx.x & 63;

    #pragma unroll
    for (int j = 0; j < 4; ++j) {
        int i = tid + j * 256;
        float ang = -6.28318530717958647692f * (float)i * (1.0f / 2048.0f);
        float sn, cs; __sincosf(ang, &sn, &cs);
        Twr[i] = cs; Twi[i] = sn;
    }
    #pragma unroll
    for (int j = 0; j < 8; ++j) { Sr[tid + j * 256] = 0.f; Si[tid + j * 256] = 0.f; }

    for (int g = 0; g < 8; ++g) {
        int d = dg * 8 + g;
        const u16* qrow = QT + ((long)b * D_MODEL + d) * L_SEQ;
        const u16* krow = KT + ((long)b * D_MODEL + d) * L_SEQ;
        __syncthreads();
        union { uint4 u; _Float16 h[8]; } xq, xk;
        xq.u = *(const uint4*)(qrow + tid * 8);
        xk.u = *(const uint4*)(krow + tid * 8);
        #pragma unroll
        for (int j = 0; j < 8; ++j) {
            int t = tid * 8 + j;
            int tr = (int)(__brev((unsigned)t) >> 21);
            Zr[tr] = (float)xq.h[j];
            Zi[tr] = (float)xk.h[j];
        }
        __syncthreads();
        fft2048_lds(Zr, Zi, Twr, Twi, tid);
        #pragma unroll
        for (int j = 0; j < 8; ++j) {
            int f = tid + j * 256;
            int fm = (2048 - f) & 2047;
            float Xr = Zr[f], Xi = Zi[f], Xmr = Zr[fm], Xmi = Zi[fm];
            float qr = 0.5f * (Xr + Xmr), qi = 0.5f * (Xi - Xmi);
            float dr = Xr - Xmr,          di = Xi + Xmi;
            float kr = 0.5f * di,         ki = -0.5f * dr;
            Sr[f] += qr * kr + qi * ki;
            Si[f] += qi * kr - qr * ki;
        }
    }
    __syncthreads();
    #pragma unroll
    for (int j = 0; j < 8; ++j) {
        int f = tid + j * 256;
        atomicAdd(&S[((long)b * 2048 + f) * 2 + 0], Sr[f]);
        atomicAdd(&S[((long)b * 2048 + f) * 2 + 1], Si[f]);
    }
}

// raw[b][tau] = (1/2048) * Re( IFFT(S[b]) )  — one block per b
__global__ __launch_bounds__(256) void fft_corr_inv(
    const float* __restrict__ S, float* __restrict__ raw)
{
    __shared__ float Zr[2048], Zi[2048];
    __shared__ float Twr[1024], Twi[1024];
    const int tid = threadIdx.x;
    const int b = blockIdx.x;

    #pragma unroll
    for (int j = 0; j < 4; ++j) {
        int i = tid + j * 256;
        float ang = 6.28318530717958647692f * (float)i * (1.0f / 2048.0f);
        float sn, cs; __sincosf(ang, &sn, &cs);
        Twr[i] = cs; Twi[i] = sn;
    }
    #pragma unroll
    for (int j = 0; j < 8; ++j) {
        int f = tid + j * 256;
        int fr = (int)(__brev((unsigned)f) >> 21);
        Zr[fr] = S[((long)b * 2048 + f) * 2 + 0];
        Zi[fr] = S[((long)b * 2048 + f) * 2 + 1];
    }
    __syncthreads();
    fft2048_lds(Zr, Zi, Twr, Twi, tid);
    #pragma unroll
    for (int j = 0; j < 8; ++j) {
        int t = tid + j * 256;
        raw[(long)b * 2048 + t] = Zr[t] * (1.0f / 2048.0f);
    }
}

// Wt[n][k] = W[k][n], fp32 -> fp16; z picks the weight matrix
__global__ __launch_bounds__(256) void transposeW4(
    const float* __restrict__ Wq, const float* __restrict__ Wk,
    const float* __restrict__ Wv, const float* __restrict__ Wo, u16* __restrict__ dstBase)
{
    __shared__ float t[32][33];
    const int z = blockIdx.z;
    const float* src = (z == 0) ? Wq : (z == 1) ? Wk : (z == 2) ? Wv : Wo;
    u16* dst = dstBase + (long)z * D_MODEL * D_MODEL;
    int tx = threadIdx.x & 31, ty = threadIdx.x >> 5;
    int c0 = blockIdx.x * 32, r0 = blockIdx.y * 32;
    #pragma unroll
    for (int r = ty; r < 32; r += 8)
        t[r][tx] = src[(long)(r0 + r) * D_MODEL + c0 + tx];
    __syncthreads();
    #pragma unroll
    for (int r = ty; r < 32; r += 8)
        dst[(long)(c0 + r) * D_MODEL + r0 + tx] = f2h(t[tx][r]);
}

// One block. g[tau] = sum_b raw[b][tau]; top-7; per-b softmax of raw[b][idx]/512.
__global__ __launch_bounds__(256) void select_topk(
    const float* __restrict__ raw, int* __restrict__ selIdx, float* __restrict__ selW)
{
    __shared__ float g[L_SEQ];
    __shared__ float rv[256];
    __shared__ int   ri[256];
    __shared__ int   sidx[TOPK];
    __shared__ float wbuf[BATCH][TOPK];
    int tid = threadIdx.x;
    for (int t = tid; t < L_SEQ; t += 256) {
        float s = 0.0f;
        #pragma unroll
        for (int b = 0; b < BATCH; ++b) s += raw[b * L_SEQ + t];
        g[t] = s;
    }
    __syncthreads();
    for (int it = 0; it < TOPK; ++it) {
        float best = -1e30f; int bi = 0x7fffffff;
        for (int t = tid; t < L_SEQ; t += 256) {
            float v = g[t];
            if (v > best || (v == best && t < bi)) { best = v; bi = t; }
        }
        rv[tid] = best; ri[tid] = bi;
        __syncthreads();
        for (int s = 128; s > 0; s >>= 1) {
            if (tid < s) {
                float v2 = rv[tid + s]; int i2 = ri[tid + s];
                if (v2 > rv[tid] || (v2 == rv[tid] && i2 < ri[tid])) { rv[tid] = v2; ri[tid] = i2; }
            }
            __syncthreads();
        }
        if (tid == 0) { sidx[it] = ri[0]; g[ri[0]] = -1e30f; }
        __syncthreads();
    }
    if (tid < BATCH * TOPK) {
        int b = tid / TOPK, k = tid % TOPK;
        wbuf[b][k] = raw[b * L_SEQ + sidx[k]] * (1.0f / 512.0f);
    }
    __syncthreads();
    if (tid < BATCH) {
        float mx = -1e30f;
        #pragma unroll
        for (int k = 0; k < TOPK; ++k) mx = fmaxf(mx, wbuf[tid][k]);
        float e[TOPK]; float sum = 0.0f;
        #pragma unroll
        for (int k = 0; k < TOPK; ++k) { e[k] = expf(wbuf[tid][k] - mx); sum += e[k]; }
        #pragma unroll
        for (int k = 0; k < TOPK; ++k) selW[tid * TOPK + k] = e[k] / sum;
    }
    if (tid < TOPK) selIdx[tid] = sidx[tid];
}

extern "C" void kernel_launch(void* const* d_in, const int* in_sizes, int n_in,
                              void* d_out, int out_size, void* d_ws, size_t ws_size,
                              hipStream_t stream)
{
    (void)in_sizes; (void)n_in; (void)out_size; (void)ws_size;
    const float* Xq = (const float*)d_in[0];
    const float* Xk = (const float*)d_in[1];
    const float* Xv = (const float*)d_in[2];
    const float* Wq = (const float*)d_in[3];
    const float* bq = (const float*)d_in[4];
    const float* Wk = (const float*)d_in[5];
    const float* bk = (const float*)d_in[6];
    const float* Wv = (const float*)d_in[7];
    const float* bv = (const float*)d_in[8];
    const float* Wo = (const float*)d_in[9];
    const float* bo = (const float*)d_in[10];

    char* ws = (char*)d_ws;
    const long SLABH = (long)BATCH * L_SEQ * D_MODEL * sizeof(u16);   // 16 MB
    u16* QT   = (u16*)(ws);
    u16* KT   = (u16*)(ws + SLABH);
    u16* Vf   = (u16*)(ws + 2 * SLABH);
    const long WSZ = (long)D_MODEL * D_MODEL;
    u16* Wt   = (u16*)(ws + 3 * SLABH);        // 4 x 512 KB: Wq,Wk,Wv,Wo transposed
    u16* Wqt = Wt + 0 * WSZ; u16* Wkt = Wt + 1 * WSZ;
    u16* Wvt = Wt + 2 * WSZ; u16* Wot = Wt + 3 * WSZ;
    float* S   = (float*)(ws + 3 * SLABH + 4 * WSZ * sizeof(u16));
    float* raw = S + (long)BATCH * L_SEQ * 2;
    int*   sIdx = (int*)(raw + (long)BATCH * L_SEQ);
    float* sW   = (float*)(sIdx + 8);

    dim3 tb(256);
    transposeW4<<<dim3(16, 16, 4), tb, 0, stream>>>(Wq, Wk, Wv, Wo, Wt);
    hipMemsetAsync(S, 0, (long)BATCH * L_SEQ * 2 * sizeof(float), stream);

    // fused Q/K/V projections (z-batched), Q/K written transposed
    dim3 gP(D_MODEL / BN, (BATCH * L_SEQ) / BM, 3);   // (4, 128, 3)
    gemm_qkv<<<gP, tb, 0, stream>>>(Xq, Xk, Xv, Wqt, Wkt, Wvt, bq, bk, bv, QT, KT, Vf);

    fft_corr_fwd<<<dim3(512), tb, 0, stream>>>(QT, KT, S);
    fft_corr_inv<<<dim3(BATCH), tb, 0, stream>>>(S, raw);
    select_topk<<<1, tb, 0, stream>>>(raw, sIdx, sW);

    // fused gather + output projection
    dim3 gO(D_MODEL / BN, (BATCH * L_SEQ) / BM, 1);   // (4, 128)
    gemm_out_fused<<<gO, tb, 0, stream>>>(Vf, Wot, sIdx, sW, bo, (float*)d_out);
}